// Round 11
// baseline (425.860 us; speedup 1.0000x reference)
//
#include <hip/hip_runtime.h>
#include <math.h>

typedef _Float16 f16;
typedef _Float16 f16x8 __attribute__((ext_vector_type(8)));
typedef float f32x4 __attribute__((ext_vector_type(4)));

#define DIM 1024
enum { MODE_K = 0, MODE_V = 1, MODE_Q = 2 };

__device__ __forceinline__ float phi_f(float x) {
  return x > 0.f ? x + 1.f : __expf(x);  // elu(x)+1
}

// global -> LDS direct DMA, 16 B per lane, wave-uniform LDS base.
typedef __attribute__((address_space(1))) const void gconst_t;
typedef __attribute__((address_space(3))) void lds_t;
__device__ __forceinline__ void g2l16(const void* g, void* l) {
  __builtin_amdgcn_global_load_lds((gconst_t*)(uintptr_t)g, (lds_t*)(uintptr_t)l, 16, 0, 0);
}

#define WAITV(n) asm volatile("s_waitcnt vmcnt(" #n ")" ::: "memory")
#define BARRIER() asm volatile("s_barrier" ::: "memory")

// ---------------- fp32 -> fp16 convert (weights) ----------------
__global__ __launch_bounds__(256) void cvt8(const float* __restrict__ src,
                                            f16* __restrict__ dst) {
  size_t i = ((size_t)blockIdx.x * 256 + threadIdx.x) * 8;
  float4 a = *(const float4*)(src + i);
  float4 b = *(const float4*)(src + i + 4);
  union { f16 h[8]; uint4 u; } p;
  p.h[0] = (f16)a.x; p.h[1] = (f16)a.y; p.h[2] = (f16)a.z; p.h[3] = (f16)a.w;
  p.h[4] = (f16)b.x; p.h[5] = (f16)b.y; p.h[6] = (f16)b.z; p.h[7] = (f16)b.w;
  *(uint4*)(dst + i) = p.u;
}

// ============ 256x128 deep-tile GEMM, A = fp32 via g2l16 (+XOR swizzle), B = f16 ============
// BM=256 BN=128 BK=32, 512 thr, 8 waves (4M x 2N -> 64x64/wave), 3-buf LDS, counted vmcnt.
// C[m,n] = epi(sum_k A[m,k] * Bw[n,k] + bias[n]); per-half rows (m_base = global offset).
template <int MODE>
__global__ __launch_bounds__(512) void gemm256_a32(const float* __restrict__ A,
                                                   const f16* __restrict__ Bw,
                                                   const float* __restrict__ bias,
                                                   const int* __restrict__ mask,
                                                   f16* __restrict__ C,
                                                   f16* __restrict__ pKs,
                                                   const float* __restrict__ Ksum,
                                                   int m_base) {
  __shared__ __attribute__((aligned(16))) float AS[3][256 * 32];  // 96 KB
  __shared__ __attribute__((aligned(16))) f16 BS[3][128 * 32];    // 24 KB
  const int tid = threadIdx.x;
  const int lane = tid & 63;
  const int l15 = lane & 15, l4 = lane >> 4;
  const int w = tid >> 6;          // 0..7
  const int wm = w >> 1, wn = w & 1;
  int nb, mb;
  {
    int flat = blockIdx.y * 8 + blockIdx.x;  // grid (8, 32)
    int wk = (flat & 7) * 32 + (flat >> 3);  // XCD-bijective
    nb = wk & 7; mb = wk >> 3;
  }
  const int n0 = nb * 128;
  const int c0 = mb * 256;       // local C row base
  const int m0 = m_base + c0;    // global A row base

  // staging coords (per lane)
  const int sa_row = w * 8 + (lane >> 3);   // + c*64 ; A rows (fp32, 128 B rows)
  const int sa_chk = lane & 7;              // 16 B chunk within row
  const int sb_row = w * 16 + (lane >> 2);  // B rows (f16, 64 B rows)
  const int sb_chk = lane & 3;

  f32x4 acc[4][4];
#pragma unroll
  for (int j = 0; j < 4; j++) {
    float bv = bias[n0 + wn * 64 + j * 16 + l15];
#pragma unroll
    for (int i = 0; i < 4; i++) acc[i][j] = (f32x4){bv, bv, bv, bv};
  }

  float ksv[4];
  if (MODE == MODE_Q) {
    const int bh = (m0 >> 12) * 16 + nb * 2 + wn;
#pragma unroll
    for (int j = 0; j < 4; j++) ksv[j] = Ksum[bh * 64 + j * 16 + l15];
  }

  auto STAGE = [&](int kt, int buf) {
#pragma unroll
    for (int c = 0; c < 4; c++) {
      int row = c * 64 + sa_row;
      g2l16(A + (size_t)(m0 + row) * DIM + kt * 32 + ((sa_chk ^ (row & 7)) << 2),
            (char*)&AS[buf][0] + c * 8192 + w * 1024);
    }
    g2l16(Bw + (size_t)(n0 + sb_row) * DIM + kt * 32 + sb_chk * 8,
          (char*)&BS[buf][0] + w * 1024);
  };

  const int swz0 = (2 * l4) ^ (l15 & 7);
  const int swz1 = (2 * l4 + 1) ^ (l15 & 7);

  // prologue: stage tiles 0,1
  STAGE(0, 0);
  STAGE(1, 1);
  WAITV(5);   // tile 0 done (tile 1's 5 ops in flight)
  BARRIER();

  for (int t = 0; t < 32; t++) {
    const int cur = t % 3;
    if (t < 30) STAGE(t + 2, (t + 2) % 3);
    // fragments
    f16x8 bf[4];
#pragma unroll
    for (int j = 0; j < 4; j++)
      bf[j] = *(f16x8*)&BS[cur][(wn * 64 + j * 16 + l15) * 32 + l4 * 8];
    f16x8 af[4];
#pragma unroll
    for (int i = 0; i < 4; i++) {
      const float* ap = &AS[cur][(wm * 64 + i * 16 + l15) * 32];
      float4 x0 = *(const float4*)(ap + swz0 * 4);
      float4 x1 = *(const float4*)(ap + swz1 * 4);
      f16x8 a;
      a[0] = (f16)x0.x; a[1] = (f16)x0.y; a[2] = (f16)x0.z; a[3] = (f16)x0.w;
      a[4] = (f16)x1.x; a[5] = (f16)x1.y; a[6] = (f16)x1.z; a[7] = (f16)x1.w;
      af[i] = a;
    }
    __builtin_amdgcn_s_setprio(1);
#pragma unroll
    for (int i = 0; i < 4; i++)
#pragma unroll
      for (int j = 0; j < 4; j++)
        acc[i][j] = __builtin_amdgcn_mfma_f32_16x16x32_f16(af[i], bf[j], acc[i][j], 0, 0, 0);
    __builtin_amdgcn_s_setprio(0);
    __builtin_amdgcn_sched_barrier(0);  // pin reads+MFMA before the tile boundary
    if (t < 30) {
      WAITV(5);       // stage(t+1) complete; stage(t+2) still in flight
      BARRIER();
    } else if (t == 30) {
      WAITV(0);       // drain stage(31)
      BARRIER();
    }
  }

  // ---- epilogues ----
  if (MODE == MODE_K) {
    float ksm[4] = {0.f, 0.f, 0.f, 0.f};
#pragma unroll
    for (int i = 0; i < 4; i++)
#pragma unroll
      for (int j = 0; j < 4; j++)
#pragma unroll
        for (int r = 0; r < 4; r++) {
          int row = wm * 64 + i * 16 + l4 * 4 + r;
          float x = phi_f(acc[i][j][r]);
          if (mask[m0 + row] == 0) x = 0.f;
          ksm[j] += x;
          C[(size_t)(c0 + row) * DIM + n0 + wn * 64 + j * 16 + l15] = (f16)x;
        }
#pragma unroll
    for (int j = 0; j < 4; j++) {
      float v = ksm[j];
      v += __shfl_xor(v, 16);
      v += __shfl_xor(v, 32);
      if (l4 == 0)
        pKs[(size_t)(mb * 4 + wm) * 1024 + n0 + wn * 64 + j * 16 + l15] = (f16)v;
    }
  } else if (MODE == MODE_V) {
#pragma unroll
    for (int i = 0; i < 4; i++)
#pragma unroll
      for (int j = 0; j < 4; j++)
#pragma unroll
        for (int r = 0; r < 4; r++) {
          int row = wm * 64 + i * 16 + l4 * 4 + r;
          C[(size_t)(c0 + row) * DIM + n0 + wn * 64 + j * 16 + l15] = (f16)acc[i][j][r];
        }
  } else {  // MODE_Q: phi + in-register Z + scale
#pragma unroll
    for (int i = 0; i < 4; i++)
#pragma unroll
      for (int r = 0; r < 4; r++) {
        float p0 = phi_f(acc[i][0][r]);
        float p1 = phi_f(acc[i][1][r]);
        float p2 = phi_f(acc[i][2][r]);
        float p3 = phi_f(acc[i][3][r]);
        float den = p0 * ksv[0] + p1 * ksv[1] + p2 * ksv[2] + p3 * ksv[3];
        den += __shfl_xor(den, 1);
        den += __shfl_xor(den, 2);
        den += __shfl_xor(den, 4);
        den += __shfl_xor(den, 8);
        float z = 1.f / den;
        int row = wm * 64 + i * 16 + l4 * 4 + r;
        size_t base = (size_t)(c0 + row) * DIM + n0 + wn * 64 + l15;
        C[base] = (f16)(p0 * z);
        C[base + 16] = (f16)(p1 * z);
        C[base + 32] = (f16)(p2 * z);
        C[base + 48] = (f16)(p3 * z);
      }
  }
}

// ============ 256x128 deep-tile GEMM, both operands f16 via g2l16 (OUT) ============
__global__ __launch_bounds__(512) void gemm256_a16(const f16* __restrict__ Ap,
                                                   const f16* __restrict__ Mh,
                                                   const float* __restrict__ bo,
                                                   float* __restrict__ Out,
                                                   int m_base) {
  __shared__ __attribute__((aligned(16))) f16 AS[3][256 * 32];  // 48 KB
  __shared__ __attribute__((aligned(16))) f16 BS[3][128 * 32];  // 24 KB
  const int tid = threadIdx.x;
  const int lane = tid & 63;
  const int l15 = lane & 15, l4 = lane >> 4;
  const int w = tid >> 6;
  const int wm = w >> 1, wn = w & 1;
  int nb, mb;
  {
    int flat = blockIdx.y * 8 + blockIdx.x;
    int wk = (flat & 7) * 32 + (flat >> 3);
    nb = wk & 7; mb = wk >> 3;
  }
  const int n0 = nb * 128;
  const int c0 = mb * 256;
  const int b = (m_base + c0) >> 12;
  const f16* B = Mh + (size_t)b * 1048576;

  const int sa_row = w * 16 + (lane >> 2);  // + c*128 ; f16 rows (64 B)
  const int sa_chk = lane & 3;
  const int sb_row = w * 16 + (lane >> 2);
  const int sb_chk = lane & 3;

  f32x4 acc[4][4];
#pragma unroll
  for (int j = 0; j < 4; j++) {
    float bv = bo[n0 + wn * 64 + j * 16 + l15];
#pragma unroll
    for (int i = 0; i < 4; i++) acc[i][j] = (f32x4){bv, bv, bv, bv};
  }

  auto STAGE = [&](int kt, int buf) {
#pragma unroll
    for (int c = 0; c < 2; c++) {
      int row = c * 128 + sa_row;
      g2l16(Ap + (size_t)(c0 + row) * DIM + kt * 32 + sa_chk * 8,
            (char*)&AS[buf][0] + c * 8192 + w * 1024);
    }
    g2l16(B + (size_t)(n0 + sb_row) * DIM + kt * 32 + sb_chk * 8,
          (char*)&BS[buf][0] + w * 1024);
  };

  STAGE(0, 0);
  STAGE(1, 1);
  WAITV(3);
  BARRIER();

  for (int t = 0; t < 32; t++) {
    const int cur = t % 3;
    if (t < 30) STAGE(t + 2, (t + 2) % 3);
    f16x8 bf[4], af[4];
#pragma unroll
    for (int j = 0; j < 4; j++)
      bf[j] = *(f16x8*)&BS[cur][(wn * 64 + j * 16 + l15) * 32 + l4 * 8];
#pragma unroll
    for (int i = 0; i < 4; i++)
      af[i] = *(f16x8*)&AS[cur][(wm * 64 + i * 16 + l15) * 32 + l4 * 8];
    __builtin_amdgcn_s_setprio(1);
#pragma unroll
    for (int i = 0; i < 4; i++)
#pragma unroll
      for (int j = 0; j < 4; j++)
        acc[i][j] = __builtin_amdgcn_mfma_f32_16x16x32_f16(af[i], bf[j], acc[i][j], 0, 0, 0);
    __builtin_amdgcn_s_setprio(0);
    __builtin_amdgcn_sched_barrier(0);
    if (t < 30) {
      WAITV(3);
      BARRIER();
    } else if (t == 30) {
      WAITV(0);
      BARRIER();
    }
  }

#pragma unroll
  for (int i = 0; i < 4; i++)
#pragma unroll
    for (int j = 0; j < 4; j++)
#pragma unroll
      for (int r = 0; r < 4; r++) {
        int row = wm * 64 + i * 16 + l4 * 4 + r;
        Out[(size_t)(m_base + c0 + row) * DIM + n0 + wn * 64 + j * 16 + l15] = acc[i][j][r];
      }
}

// ---------------- KV via MFMA (unchanged) ----------------
__global__ __launch_bounds__(256) void kv_mfma(const f16* __restrict__ Kp,
                                               const f16* __restrict__ Vp,
                                               f16* __restrict__ pKV) {
  __shared__ f16 KT[64][66];
  __shared__ f16 VT[64][66];
  const int tid = threadIdx.x;
  const int lane = tid & 63;
  const int l15 = lane & 15, l4 = lane >> 4, w = tid >> 6;
  const int h = blockIdx.x;
  const int ck = blockIdx.y;
  const int bl = ck >> 3;
  const int srow0 = bl * 4096 + (ck & 7) * 512;
  const int s_loc = tid >> 2;
  const int c0 = (tid & 3) * 16;

  f32x4 acc[4];
#pragma unroll
  for (int j = 0; j < 4; j++) acc[j] = (f32x4){0.f, 0.f, 0.f, 0.f};

  for (int sub = 0; sub < 8; sub++) {
    const size_t gbase = (size_t)(srow0 + sub * 64 + s_loc) * DIM + h * 64 + c0;
    f16x8 k0 = *(const f16x8*)(Kp + gbase);
    f16x8 k1 = *(const f16x8*)(Kp + gbase + 8);
    f16x8 v0 = *(const f16x8*)(Vp + gbase);
    f16x8 v1 = *(const f16x8*)(Vp + gbase + 8);
    __syncthreads();
#pragma unroll
    for (int q = 0; q < 8; q++) {
      KT[c0 + q][s_loc] = k0[q];
      KT[c0 + 8 + q][s_loc] = k1[q];
      VT[c0 + q][s_loc] = v0[q];
      VT[c0 + 8 + q][s_loc] = v1[q];
    }
    __syncthreads();
#pragma unroll
    for (int ks = 0; ks < 2; ks++) {
      f16x8 af = *(f16x8*)&KT[w * 16 + l15][ks * 32 + l4 * 8];
#pragma unroll
      for (int j = 0; j < 4; j++) {
        f16x8 bfr = *(f16x8*)&VT[j * 16 + l15][ks * 32 + l4 * 8];
        acc[j] = __builtin_amdgcn_mfma_f32_16x16x32_f16(af, bfr, acc[j], 0, 0, 0);
      }
    }
  }
  f16* dst = pKV + (size_t)(h * 16 + ck) * 4096;
#pragma unroll
  for (int j = 0; j < 4; j++)
#pragma unroll
    for (int r = 0; r < 4; r++)
      dst[(w * 16 + l4 * 4 + r) * 64 + j * 16 + l15] = (f16)acc[j][r];
}

// ---------------- reduce (unchanged) ----------------
__global__ __launch_bounds__(256) void kv_reduce(const f16* __restrict__ pKV,
                                                 const f16* __restrict__ pKs,
                                                 f16* __restrict__ KVdh,
                                                 float* __restrict__ Ksum,
                                                 int half) {
  const int bh_l = blockIdx.x;
  const int h = bh_l & 15, bl = bh_l >> 4;
  const int bh = half * 32 + bh_l;
  const int tid = threadIdx.x;
  for (int cell = tid; cell < 4096; cell += 256) {
    float s = 0.f;
#pragma unroll
    for (int c = 0; c < 8; c++) s += (float)pKV[(size_t)(h * 16 + bl * 8 + c) * 4096 + cell];
    KVdh[(size_t)bh * 4096 + cell] = (f16)s;
  }
  if (tid < 64) {
    float s = 0.f;
#pragma unroll
    for (int y = 0; y < 64; y++) s += (float)pKs[(size_t)(bl * 64 + y) * 1024 + h * 64 + tid];
    Ksum[bh * 64 + tid] = s + 1e-6f;
  }
}

// ---------------- M precompute (unchanged) ----------------
__global__ __launch_bounds__(256) void m_kernel(const f16* __restrict__ Woh,
                                                const f16* __restrict__ KVdh,
                                                f16* __restrict__ Mh) {
  __shared__ __attribute__((aligned(16))) f16 As[128][64];
  __shared__ __attribute__((aligned(16))) f16 Bs[64][64];
  const int tid = threadIdx.x;
  const int lane = tid & 63;
  const int l15 = lane & 15, l4 = lane >> 4, w = tid >> 6;
  const int n0 = blockIdx.x * 128;
  const int bh = blockIdx.y;
  const int b = bh >> 4, h = bh & 15;

#pragma unroll
  for (int c = 0; c < 4; c++) {
    int row = w * 32 + c * 8 + (lane >> 3);
    int col = (lane & 7) * 8;
    g2l16(Woh + (size_t)(n0 + row) * DIM + h * 64 + col, (char*)As + w * 4096 + c * 1024);
  }
#pragma unroll
  for (int c = 0; c < 2; c++) {
    int row = w * 16 + c * 8 + (lane >> 3);
    int col = (lane & 7) * 8;
    g2l16(KVdh + (size_t)bh * 4096 + row * 64 + col, (char*)Bs + w * 2048 + c * 1024);
  }
  __syncthreads();

  f32x4 acc[2][4];
#pragma unroll
  for (int i = 0; i < 2; i++)
#pragma unroll
    for (int j = 0; j < 4; j++) acc[i][j] = (f32x4){0.f, 0.f, 0.f, 0.f};
#pragma unroll
  for (int ks = 0; ks < 2; ks++) {
    f16x8 af[2], bfr[4];
#pragma unroll
    for (int i = 0; i < 2; i++)
      af[i] = *(f16x8*)&As[w * 32 + i * 16 + l15][ks * 32 + l4 * 8];
#pragma unroll
    for (int j = 0; j < 4; j++)
      bfr[j] = *(f16x8*)&Bs[j * 16 + l15][ks * 32 + l4 * 8];
#pragma unroll
    for (int i = 0; i < 2; i++)
#pragma unroll
      for (int j = 0; j < 4; j++)
        acc[i][j] = __builtin_amdgcn_mfma_f32_16x16x32_f16(af[i], bfr[j], acc[i][j], 0, 0, 0);
  }
#pragma unroll
  for (int i = 0; i < 2; i++)
#pragma unroll
    for (int j = 0; j < 4; j++)
#pragma unroll
      for (int r = 0; r < 4; r++) {
        int nl = n0 + w * 32 + i * 16 + l4 * 4 + r;
        Mh[(size_t)b * 1048576 + (size_t)nl * DIM + h * 64 + j * 16 + l15] = (f16)acc[i][j][r];
      }
}

extern "C" void kernel_launch(void* const* d_in, const int* in_sizes, int n_in,
                              void* d_out, int out_size, void* d_ws, size_t ws_size,
                              hipStream_t stream) {
  (void)in_sizes; (void)n_in; (void)out_size; (void)ws_size;
  const float* query = (const float*)d_in[0];
  const float* key = (const float*)d_in[1];
  const float* value = (const float*)d_in[2];
  const int* kmask = (const int*)d_in[3];
  const float* Wq = (const float*)d_in[4];
  const float* bq = (const float*)d_in[5];
  const float* Wk = (const float*)d_in[6];
  const float* bk = (const float*)d_in[7];
  const float* Wv = (const float*)d_in[8];
  const float* bv = (const float*)d_in[9];
  const float* Wo = (const float*)d_in[10];
  const float* bo = (const float*)d_in[11];

  // workspace (peak ~42.8 MiB; well under proven 55.1)
  char* ws = (char*)d_ws;
  const size_t MB = 1 << 20;
  f16* W0 = (f16*)(ws);                // Wkh
  f16* W1 = (f16*)(ws + 2 * MB);       // Wvh
  f16* W2 = (f16*)(ws + 4 * MB);       // Wqh
  f16* W3 = (f16*)(ws + 6 * MB);       // Woh
  f16* Kp = (f16*)(ws + 8 * MB);       // 16 MiB (half) ; stage2: Ap
  f16* Vp = (f16*)(ws + 24 * MB);      // 16 MiB (half) ; stage2: Mh (8 MiB)
  f16* pKV = (f16*)(ws + 40 * MB);     // 2 MiB
  f16* pKs = (f16*)(ws + 42 * MB);     // 256 KiB ([128][1024] per half)
  f16* KVdh = (f16*)(ws + 42 * MB + 256 * 1024);      // 512 KiB
  float* Ksum = (float*)(ws + 42 * MB + 768 * 1024);  // 16 KiB
  f16* Ap = Kp;
  f16* Mh = Vp;

  dim3 blk256(256), blk512(512);
  dim3 ggrid(8, 32);  // 256 blocks, BM=256 x BN=128 over M=8192, N=1024
  cvt8<<<512, blk256, 0, stream>>>(Wk, W0);
  cvt8<<<512, blk256, 0, stream>>>(Wv, W1);
  cvt8<<<512, blk256, 0, stream>>>(Wq, W2);
  cvt8<<<512, blk256, 0, stream>>>(Wo, W3);

  // stage 1: per-half K/V projections (deep-tile) + MFMA KV partials
  for (int half = 0; half < 2; half++) {
    int mb = half * 8192;
    gemm256_a32<MODE_K><<<ggrid, blk512, 0, stream>>>(key, W0, bk, kmask, Kp, pKs, nullptr, mb);
    gemm256_a32<MODE_V><<<ggrid, blk512, 0, stream>>>(value, W1, bv, nullptr, Vp, nullptr, nullptr, mb);
    kv_mfma<<<dim3(16, 16), blk256, 0, stream>>>(Kp, Vp, pKV);
    kv_reduce<<<32, blk256, 0, stream>>>(pKV, pKs, KVdh, Ksum, half);
  }

  // stage 2: M precompute, per-half Q -> A' and OUT
  m_kernel<<<dim3(8, 64), blk256, 0, stream>>>(W3, KVdh, Mh);
  for (int half = 0; half < 2; half++) {
    int mb = half * 8192;
    gemm256_a32<MODE_Q><<<ggrid, blk512, 0, stream>>>(query, W2, bq, nullptr, Ap, nullptr, Ksum, mb);
    gemm256_a16<<<ggrid, blk512, 0, stream>>>(Ap, Mh, bo, (float*)d_out, mb);
  }
}

// Round 12
// 312.808 us; speedup vs baseline: 1.3614x; 1.3614x over previous
//
#include <hip/hip_runtime.h>
#include <math.h>

typedef _Float16 f16;
typedef _Float16 f16x8 __attribute__((ext_vector_type(8)));
typedef float f32x4 __attribute__((ext_vector_type(4)));

#define DIM 1024
enum { MODE_K = 0, MODE_V = 1, MODE_Q = 2 };

__device__ __forceinline__ float phi_f(float x) {
  return x > 0.f ? x + 1.f : __expf(x);  // elu(x)+1
}

// global -> LDS direct DMA, 16 B per lane, wave-uniform LDS base.
typedef __attribute__((address_space(1))) const void gconst_t;
typedef __attribute__((address_space(3))) void lds_t;
__device__ __forceinline__ void g2l16(const void* g, void* l) {
  __builtin_amdgcn_global_load_lds((gconst_t*)(uintptr_t)g, (lds_t*)(uintptr_t)l, 16, 0, 0);
}

// XCD-bijective swizzle for grid (8, 64) = 512 blocks.
__device__ __forceinline__ void swz_8x64(int& nb, int& mb) {
  int flat = blockIdx.y * 8 + blockIdx.x;
  int wk = (flat & 7) * 64 + (flat >> 3);
  nb = wk & 7;
  mb = wk >> 3;
}

// ---------------- fp32 -> fp16 convert (weights only) ----------------
__global__ __launch_bounds__(256) void cvt8(const float* __restrict__ src,
                                            f16* __restrict__ dst) {
  size_t i = ((size_t)blockIdx.x * 256 + threadIdx.x) * 8;
  float4 a = *(const float4*)(src + i);
  float4 b = *(const float4*)(src + i + 4);
  union { f16 h[8]; uint4 u; } p;
  p.h[0] = (f16)a.x; p.h[1] = (f16)a.y; p.h[2] = (f16)a.z; p.h[3] = (f16)a.w;
  p.h[4] = (f16)b.x; p.h[5] = (f16)b.y; p.h[6] = (f16)b.z; p.h[7] = (f16)b.w;
  *(uint4*)(dst + i) = p.u;
}

// ============ 128x128 2-phase GEMM, A = fp32 via g2l16 + XOR swizzle, B = f16 same ============
// C[m,n] = epi(sum_k A[m,k]*Bw[n,k] + bias[n]); per-half rows.
template <int MODE>
__global__ __launch_bounds__(256) void gemm_a32(const float* __restrict__ A,
                                                const f16* __restrict__ Bw,
                                                const float* __restrict__ bias,
                                                const int* __restrict__ mask,
                                                f16* __restrict__ C,
                                                f16* __restrict__ pKs,
                                                const float* __restrict__ Ksum,
                                                int m_base) {
  __shared__ __attribute__((aligned(16))) float AS[128 * 64];  // 32 KB
  __shared__ __attribute__((aligned(16))) f16 BS[128 * 64];    // 16 KB
  const int tid = threadIdx.x;
  const int lane = tid & 63;
  const int l15 = lane & 15, l4 = lane >> 4;
  const int w = tid >> 6, wr = w >> 1, wc = w & 1;
  int nb, mb;
  swz_8x64(nb, mb);
  const int n0 = nb * 128;
  const int c0 = mb * 128;
  const int m0 = m_base + c0;

  f32x4 acc[4][4];
#pragma unroll
  for (int j = 0; j < 4; j++) {
    float bv = bias[n0 + wc * 64 + j * 16 + l15];
#pragma unroll
    for (int i = 0; i < 4; i++) acc[i][j] = (f32x4){bv, bv, bv, bv};
  }

  float ksv[4];
  if (MODE == MODE_Q) {
    const int bh = (m0 >> 12) * 16 + nb * 2 + wc;
#pragma unroll
    for (int j = 0; j < 4; j++) ksv[j] = Ksum[bh * 64 + j * 16 + l15];
  }

  for (int kt = 0; kt < DIM; kt += 64) {
    __syncthreads();
    // B: f16 [128][64], rows 128 B = 8 chunks; source pre-swizzled chunk^(row&7)
#pragma unroll
    for (int c = 0; c < 4; c++) {
      int row = w * 32 + c * 8 + (lane >> 3);
      int sc = (lane & 7) ^ (row & 7);
      g2l16(Bw + (size_t)(n0 + row) * DIM + kt + sc * 8,
            (char*)BS + w * 4096 + c * 1024);
    }
    // A: fp32 [128][64], rows 256 B = 16 chunks; source pre-swizzled low3
#pragma unroll
    for (int c = 0; c < 8; c++) {
      int row = w * 32 + c * 4 + (lane >> 4);
      int sc = (lane & 15) ^ (row & 7);
      g2l16(A + (size_t)(m0 + row) * DIM + kt + sc * 4,
            (char*)AS + w * 8192 + c * 1024);
    }
    __syncthreads();
#pragma unroll
    for (int ks = 0; ks < 2; ks++) {
      f16x8 bf[4], af[4];
#pragma unroll
      for (int j = 0; j < 4; j++) {
        int row = wc * 64 + j * 16 + l15;
        int ch = (ks * 4 + l4) ^ (row & 7);
        bf[j] = *(f16x8*)((char*)BS + row * 128 + ch * 16);
      }
#pragma unroll
      for (int i = 0; i < 4; i++) {
        int row = wr * 64 + i * 16 + l15;
        int s = ks * 8 + 2 * l4;
        int ch0 = s ^ (row & 7), ch1 = (s + 1) ^ (row & 7);
        float4 x0 = *(const float4*)((char*)AS + row * 256 + ch0 * 16);
        float4 x1 = *(const float4*)((char*)AS + row * 256 + ch1 * 16);
        f16x8 a;
        a[0] = (f16)x0.x; a[1] = (f16)x0.y; a[2] = (f16)x0.z; a[3] = (f16)x0.w;
        a[4] = (f16)x1.x; a[5] = (f16)x1.y; a[6] = (f16)x1.z; a[7] = (f16)x1.w;
        af[i] = a;
      }
#pragma unroll
      for (int i = 0; i < 4; i++)
#pragma unroll
        for (int j = 0; j < 4; j++)
          acc[i][j] = __builtin_amdgcn_mfma_f32_16x16x32_f16(af[i], bf[j], acc[i][j], 0, 0, 0);
    }
  }

  // ---- epilogues ----
  if (MODE == MODE_K) {
    float ksm[4] = {0.f, 0.f, 0.f, 0.f};
#pragma unroll
    for (int i = 0; i < 4; i++)
#pragma unroll
      for (int j = 0; j < 4; j++)
#pragma unroll
        for (int r = 0; r < 4; r++) {
          int row = wr * 64 + i * 16 + l4 * 4 + r;
          float x = phi_f(acc[i][j][r]);
          if (mask[m0 + row] == 0) x = 0.f;
          ksm[j] += x;
          C[(size_t)(c0 + row) * DIM + n0 + wc * 64 + j * 16 + l15] = (f16)x;
        }
#pragma unroll
    for (int j = 0; j < 4; j++) {
      float v = ksm[j];
      v += __shfl_xor(v, 16);
      v += __shfl_xor(v, 32);
      if (l4 == 0)
        pKs[(size_t)(mb * 2 + wr) * 1024 + n0 + wc * 64 + j * 16 + l15] = (f16)v;
    }
  } else if (MODE == MODE_V) {
#pragma unroll
    for (int i = 0; i < 4; i++)
#pragma unroll
      for (int j = 0; j < 4; j++)
#pragma unroll
        for (int r = 0; r < 4; r++) {
          int row = wr * 64 + i * 16 + l4 * 4 + r;
          C[(size_t)(c0 + row) * DIM + n0 + wc * 64 + j * 16 + l15] = (f16)acc[i][j][r];
        }
  } else {  // MODE_Q: phi + in-register Z + scale
#pragma unroll
    for (int i = 0; i < 4; i++)
#pragma unroll
      for (int r = 0; r < 4; r++) {
        float p0 = phi_f(acc[i][0][r]);
        float p1 = phi_f(acc[i][1][r]);
        float p2 = phi_f(acc[i][2][r]);
        float p3 = phi_f(acc[i][3][r]);
        float den = p0 * ksv[0] + p1 * ksv[1] + p2 * ksv[2] + p3 * ksv[3];
        den += __shfl_xor(den, 1);
        den += __shfl_xor(den, 2);
        den += __shfl_xor(den, 4);
        den += __shfl_xor(den, 8);
        float z = 1.f / den;
        int row = wr * 64 + i * 16 + l4 * 4 + r;
        size_t base = (size_t)(c0 + row) * DIM + n0 + wc * 64 + l15;
        C[base] = (f16)(p0 * z);
        C[base + 16] = (f16)(p1 * z);
        C[base + 32] = (f16)(p2 * z);
        C[base + 48] = (f16)(p3 * z);
      }
  }
}

// ============ 128x128 2-phase GEMM, both operands f16 via g2l16 + XOR swizzle (OUT) ============
__global__ __launch_bounds__(256) void gemm_out(const f16* __restrict__ Ap,
                                                const f16* __restrict__ Mh,
                                                const float* __restrict__ bo,
                                                float* __restrict__ Out,
                                                int m_base) {
  __shared__ __attribute__((aligned(16))) f16 AS[128 * 64];  // 16 KB
  __shared__ __attribute__((aligned(16))) f16 BS[128 * 64];  // 16 KB
  const int tid = threadIdx.x;
  const int lane = tid & 63;
  const int l15 = lane & 15, l4 = lane >> 4;
  const int w = tid >> 6, wr = w >> 1, wc = w & 1;
  int nb, mb;
  swz_8x64(nb, mb);
  const int n0 = nb * 128;
  const int c0 = mb * 128;
  const int b = (m_base + c0) >> 12;
  const f16* B = Mh + (size_t)b * 1048576;

  f32x4 acc[4][4];
#pragma unroll
  for (int j = 0; j < 4; j++) {
    float bv = bo[n0 + wc * 64 + j * 16 + l15];
#pragma unroll
    for (int i = 0; i < 4; i++) acc[i][j] = (f32x4){bv, bv, bv, bv};
  }

  for (int kt = 0; kt < DIM; kt += 64) {
    __syncthreads();
#pragma unroll
    for (int c = 0; c < 4; c++) {
      int row = w * 32 + c * 8 + (lane >> 3);
      int sc = (lane & 7) ^ (row & 7);
      g2l16(Ap + (size_t)(c0 + row) * DIM + kt + sc * 8,
            (char*)AS + w * 4096 + c * 1024);
      g2l16(B + (size_t)(n0 + row) * DIM + kt + sc * 8,
            (char*)BS + w * 4096 + c * 1024);
    }
    __syncthreads();
#pragma unroll
    for (int ks = 0; ks < 2; ks++) {
      f16x8 af[4], bf[4];
#pragma unroll
      for (int i = 0; i < 4; i++) {
        int row = wr * 64 + i * 16 + l15;
        int ch = (ks * 4 + l4) ^ (row & 7);
        af[i] = *(f16x8*)((char*)AS + row * 128 + ch * 16);
      }
#pragma unroll
      for (int j = 0; j < 4; j++) {
        int row = wc * 64 + j * 16 + l15;
        int ch = (ks * 4 + l4) ^ (row & 7);
        bf[j] = *(f16x8*)((char*)BS + row * 128 + ch * 16);
      }
#pragma unroll
      for (int i = 0; i < 4; i++)
#pragma unroll
        for (int j = 0; j < 4; j++)
          acc[i][j] = __builtin_amdgcn_mfma_f32_16x16x32_f16(af[i], bf[j], acc[i][j], 0, 0, 0);
    }
  }

#pragma unroll
  for (int i = 0; i < 4; i++)
#pragma unroll
    for (int j = 0; j < 4; j++) {
      const int rl = wr * 64 + i * 16 + l4 * 4;
      const int gn = n0 + wc * 64 + j * 16 + l15;
#pragma unroll
      for (int r = 0; r < 4; r++)
        Out[(size_t)(m_base + c0 + rl + r) * DIM + gn] = acc[i][j][r];
    }
}

// ---------------- KV via MFMA (unchanged) ----------------
__global__ __launch_bounds__(256) void kv_mfma(const f16* __restrict__ Kp,
                                               const f16* __restrict__ Vp,
                                               f16* __restrict__ pKV) {
  __shared__ f16 KT[64][66];
  __shared__ f16 VT[64][66];
  const int tid = threadIdx.x;
  const int lane = tid & 63;
  const int l15 = lane & 15, l4 = lane >> 4, w = tid >> 6;
  const int h = blockIdx.x;
  const int ck = blockIdx.y;
  const int bl = ck >> 3;
  const int srow0 = bl * 4096 + (ck & 7) * 512;
  const int s_loc = tid >> 2;
  const int c0 = (tid & 3) * 16;

  f32x4 acc[4];
#pragma unroll
  for (int j = 0; j < 4; j++) acc[j] = (f32x4){0.f, 0.f, 0.f, 0.f};

  for (int sub = 0; sub < 8; sub++) {
    const size_t gbase = (size_t)(srow0 + sub * 64 + s_loc) * DIM + h * 64 + c0;
    f16x8 k0 = *(const f16x8*)(Kp + gbase);
    f16x8 k1 = *(const f16x8*)(Kp + gbase + 8);
    f16x8 v0 = *(const f16x8*)(Vp + gbase);
    f16x8 v1 = *(const f16x8*)(Vp + gbase + 8);
    __syncthreads();
#pragma unroll
    for (int q = 0; q < 8; q++) {
      KT[c0 + q][s_loc] = k0[q];
      KT[c0 + 8 + q][s_loc] = k1[q];
      VT[c0 + q][s_loc] = v0[q];
      VT[c0 + 8 + q][s_loc] = v1[q];
    }
    __syncthreads();
#pragma unroll
    for (int ks = 0; ks < 2; ks++) {
      f16x8 af = *(f16x8*)&KT[w * 16 + l15][ks * 32 + l4 * 8];
#pragma unroll
      for (int j = 0; j < 4; j++) {
        f16x8 bfr = *(f16x8*)&VT[j * 16 + l15][ks * 32 + l4 * 8];
        acc[j] = __builtin_amdgcn_mfma_f32_16x16x32_f16(af, bfr, acc[j], 0, 0, 0);
      }
    }
  }
  f16* dst = pKV + (size_t)(h * 16 + ck) * 4096;
#pragma unroll
  for (int j = 0; j < 4; j++)
#pragma unroll
    for (int r = 0; r < 4; r++)
      dst[(w * 16 + l4 * 4 + r) * 64 + j * 16 + l15] = (f16)acc[j][r];
}

// ---------------- reduce (unchanged) ----------------
__global__ __launch_bounds__(256) void kv_reduce(const f16* __restrict__ pKV,
                                                 const f16* __restrict__ pKs,
                                                 f16* __restrict__ KVdh,
                                                 float* __restrict__ Ksum,
                                                 int half) {
  const int bh_l = blockIdx.x;
  const int h = bh_l & 15, bl = bh_l >> 4;
  const int bh = half * 32 + bh_l;
  const int tid = threadIdx.x;
  for (int cell = tid; cell < 4096; cell += 256) {
    float s = 0.f;
#pragma unroll
    for (int c = 0; c < 8; c++) s += (float)pKV[(size_t)(h * 16 + bl * 8 + c) * 4096 + cell];
    KVdh[(size_t)bh * 4096 + cell] = (f16)s;
  }
  if (tid < 64) {
    float s = 0.f;
#pragma unroll
    for (int y = 0; y < 64; y++) s += (float)pKs[(size_t)(bl * 64 + y) * 1024 + h * 64 + tid];
    Ksum[bh * 64 + tid] = s + 1e-6f;
  }
}

// ---------------- M precompute (unchanged) ----------------
__global__ __launch_bounds__(256) void m_kernel(const f16* __restrict__ Woh,
                                                const f16* __restrict__ KVdh,
                                                f16* __restrict__ Mh) {
  __shared__ __attribute__((aligned(16))) f16 As[128][64];
  __shared__ __attribute__((aligned(16))) f16 Bs[64][64];
  const int tid = threadIdx.x;
  const int lane = tid & 63;
  const int l15 = lane & 15, l4 = lane >> 4, w = tid >> 6;
  const int n0 = blockIdx.x * 128;
  const int bh = blockIdx.y;
  const int b = bh >> 4, h = bh & 15;

#pragma unroll
  for (int c = 0; c < 4; c++) {
    int row = w * 32 + c * 8 + (lane >> 3);
    int col = (lane & 7) * 8;
    g2l16(Woh + (size_t)(n0 + row) * DIM + h * 64 + col, (char*)As + w * 4096 + c * 1024);
  }
#pragma unroll
  for (int c = 0; c < 2; c++) {
    int row = w * 16 + c * 8 + (lane >> 3);
    int col = (lane & 7) * 8;
    g2l16(KVdh + (size_t)bh * 4096 + row * 64 + col, (char*)Bs + w * 2048 + c * 1024);
  }
  __syncthreads();

  f32x4 acc[2][4];
#pragma unroll
  for (int i = 0; i < 2; i++)
#pragma unroll
    for (int j = 0; j < 4; j++) acc[i][j] = (f32x4){0.f, 0.f, 0.f, 0.f};
#pragma unroll
  for (int ks = 0; ks < 2; ks++) {
    f16x8 af[2], bfr[4];
#pragma unroll
    for (int i = 0; i < 2; i++)
      af[i] = *(f16x8*)&As[w * 32 + i * 16 + l15][ks * 32 + l4 * 8];
#pragma unroll
    for (int j = 0; j < 4; j++)
      bfr[j] = *(f16x8*)&Bs[j * 16 + l15][ks * 32 + l4 * 8];
#pragma unroll
    for (int i = 0; i < 2; i++)
#pragma unroll
      for (int j = 0; j < 4; j++)
        acc[i][j] = __builtin_amdgcn_mfma_f32_16x16x32_f16(af[i], bfr[j], acc[i][j], 0, 0, 0);
  }
#pragma unroll
  for (int i = 0; i < 2; i++)
#pragma unroll
    for (int j = 0; j < 4; j++)
#pragma unroll
      for (int r = 0; r < 4; r++) {
        int nl = n0 + w * 32 + i * 16 + l4 * 4 + r;
        Mh[(size_t)b * 1048576 + (size_t)nl * DIM + h * 64 + j * 16 + l15] = (f16)acc[i][j][r];
      }
}

extern "C" void kernel_launch(void* const* d_in, const int* in_sizes, int n_in,
                              void* d_out, int out_size, void* d_ws, size_t ws_size,
                              hipStream_t stream) {
  (void)in_sizes; (void)n_in; (void)out_size; (void)ws_size;
  const float* query = (const float*)d_in[0];
  const float* key = (const float*)d_in[1];
  const float* value = (const float*)d_in[2];
  const int* kmask = (const int*)d_in[3];
  const float* Wq = (const float*)d_in[4];
  const float* bq = (const float*)d_in[5];
  const float* Wk = (const float*)d_in[6];
  const float* bk = (const float*)d_in[7];
  const float* Wv = (const float*)d_in[8];
  const float* bv = (const float*)d_in[9];
  const float* Wo = (const float*)d_in[10];
  const float* bo = (const float*)d_in[11];

  // workspace (peak ~42.8 MiB; under proven 55.1)
  char* ws = (char*)d_ws;
  const size_t MB = 1 << 20;
  f16* W0 = (f16*)(ws);                // Wkh
  f16* W1 = (f16*)(ws + 2 * MB);       // Wvh
  f16* W2 = (f16*)(ws + 4 * MB);       // Wqh
  f16* W3 = (f16*)(ws + 6 * MB);       // Woh
  f16* Kp = (f16*)(ws + 8 * MB);       // 16 MiB (half) ; stage2: Ap
  f16* Vp = (f16*)(ws + 24 * MB);      // 16 MiB (half) ; stage2: Mh (8 MiB)
  f16* pKV = (f16*)(ws + 40 * MB);     // 2 MiB
  f16* pKs = (f16*)(ws + 42 * MB);     // 256 KiB ([128][1024] per half)
  f16* KVdh = (f16*)(ws + 42 * MB + 256 * 1024);      // 512 KiB
  float* Ksum = (float*)(ws + 42 * MB + 768 * 1024);  // 16 KiB
  f16* Ap = Kp;
  f16* Mh = Vp;

  dim3 blk(256);
  dim3 ghalf(8, 64);
  cvt8<<<512, blk, 0, stream>>>(Wk, W0);
  cvt8<<<512, blk, 0, stream>>>(Wv, W1);
  cvt8<<<512, blk, 0, stream>>>(Wq, W2);
  cvt8<<<512, blk, 0, stream>>>(Wo, W3);

  // stage 1: per-half K/V projections + MFMA KV partials
  for (int half = 0; half < 2; half++) {
    int mb = half * 8192;
    gemm_a32<MODE_K><<<ghalf, blk, 0, stream>>>(key, W0, bk, kmask, Kp, pKs, nullptr, mb);
    gemm_a32<MODE_V><<<ghalf, blk, 0, stream>>>(value, W1, bv, nullptr, Vp, nullptr, nullptr, mb);
    kv_mfma<<<dim3(16, 16), blk, 0, stream>>>(Kp, Vp, pKV);
    kv_reduce<<<32, blk, 0, stream>>>(pKV, pKs, KVdh, Ksum, half);
  }

  // stage 2: M precompute, per-half Q -> A' and OUT
  m_kernel<<<dim3(8, 64), blk, 0, stream>>>(W3, KVdh, Mh);
  for (int half = 0; half < 2; half++) {
    int mb = half * 8192;
    gemm_a32<MODE_Q><<<ghalf, blk, 0, stream>>>(query, W2, bq, nullptr, Ap, nullptr, Ksum, mb);
    gemm_out<<<ghalf, blk, 0, stream>>>(Ap, Mh, bo, (float*)d_out, mb);
  }
}

// Round 13
// 310.714 us; speedup vs baseline: 1.3706x; 1.0067x over previous
//
#include <hip/hip_runtime.h>
#include <math.h>

typedef _Float16 f16;
typedef _Float16 f16x8 __attribute__((ext_vector_type(8)));
typedef float f32x4 __attribute__((ext_vector_type(4)));

#define DIM 1024
enum { MODE_K = 0, MODE_V = 1, MODE_Q = 2 };

__device__ __forceinline__ float phi_f(float x) {
  return x > 0.f ? x + 1.f : __expf(x);  // elu(x)+1
}

// global -> LDS direct DMA, 16 B per lane, wave-uniform LDS base.
typedef __attribute__((address_space(1))) const void gconst_t;
typedef __attribute__((address_space(3))) void lds_t;
__device__ __forceinline__ void g2l16(const void* g, void* l) {
  __builtin_amdgcn_global_load_lds((gconst_t*)(uintptr_t)g, (lds_t*)(uintptr_t)l, 16, 0, 0);
}

// XCD-bijective swizzle for grid (8, 64) = 512 blocks.
__device__ __forceinline__ void swz_8x64(int& nb, int& mb) {
  int flat = blockIdx.y * 8 + blockIdx.x;
  int wk = (flat & 7) * 64 + (flat >> 3);
  nb = wk & 7;
  mb = wk >> 3;
}

// ---------------- fp32 -> fp16 convert (weights and input halves) ----------------
__global__ __launch_bounds__(256) void cvt8(const float* __restrict__ src,
                                            f16* __restrict__ dst) {
  size_t i = ((size_t)blockIdx.x * 256 + threadIdx.x) * 8;
  float4 a = *(const float4*)(src + i);
  float4 b = *(const float4*)(src + i + 4);
  union { f16 h[8]; uint4 u; } p;
  p.h[0] = (f16)a.x; p.h[1] = (f16)a.y; p.h[2] = (f16)a.z; p.h[3] = (f16)a.w;
  p.h[4] = (f16)b.x; p.h[5] = (f16)b.y; p.h[6] = (f16)b.z; p.h[7] = (f16)b.w;
  *(uint4*)(dst + i) = p.u;
}

// ============ 128x128 2-phase GEMM, BOTH operands f16 via g2l16 + XOR swizzle ============
// C[m,n] = epi(sum_k A[m,k]*Bw[n,k] + bias[n]); A is half-local f16 (row = c0+...).
template <int MODE>
__global__ __launch_bounds__(256) void gemm_f16(const f16* __restrict__ A,
                                                const f16* __restrict__ Bw,
                                                const float* __restrict__ bias,
                                                const int* __restrict__ mask,
                                                f16* __restrict__ C,
                                                f16* __restrict__ pKs,
                                                const float* __restrict__ Ksum,
                                                int m_base) {
  __shared__ __attribute__((aligned(16))) f16 AS[128 * 64];  // 16 KB
  __shared__ __attribute__((aligned(16))) f16 BS[128 * 64];  // 16 KB
  const int tid = threadIdx.x;
  const int lane = tid & 63;
  const int l15 = lane & 15, l4 = lane >> 4;
  const int w = tid >> 6, wr = w >> 1, wc = w & 1;
  int nb, mb;
  swz_8x64(nb, mb);
  const int n0 = nb * 128;
  const int c0 = mb * 128;      // local row base (A, C)
  const int m0 = m_base + c0;   // global row base (mask, Ksum batch)

  f32x4 acc[4][4];
#pragma unroll
  for (int j = 0; j < 4; j++) {
    float bv = bias[n0 + wc * 64 + j * 16 + l15];
#pragma unroll
    for (int i = 0; i < 4; i++) acc[i][j] = (f32x4){bv, bv, bv, bv};
  }

  float ksv[4];
  if (MODE == MODE_Q) {
    const int bh = (m0 >> 12) * 16 + nb * 2 + wc;
#pragma unroll
    for (int j = 0; j < 4; j++) ksv[j] = Ksum[bh * 64 + j * 16 + l15];
  }

  for (int kt = 0; kt < DIM; kt += 64) {
    __syncthreads();
#pragma unroll
    for (int c = 0; c < 4; c++) {
      int row = w * 32 + c * 8 + (lane >> 3);
      int sc = (lane & 7) ^ (row & 7);
      g2l16(A + (size_t)(c0 + row) * DIM + kt + sc * 8,
            (char*)AS + w * 4096 + c * 1024);
      g2l16(Bw + (size_t)(n0 + row) * DIM + kt + sc * 8,
            (char*)BS + w * 4096 + c * 1024);
    }
    __syncthreads();
#pragma unroll
    for (int ks = 0; ks < 2; ks++) {
      f16x8 af[4], bf[4];
#pragma unroll
      for (int i = 0; i < 4; i++) {
        int row = wr * 64 + i * 16 + l15;
        int ch = (ks * 4 + l4) ^ (row & 7);
        af[i] = *(f16x8*)((char*)AS + row * 128 + ch * 16);
      }
#pragma unroll
      for (int j = 0; j < 4; j++) {
        int row = wc * 64 + j * 16 + l15;
        int ch = (ks * 4 + l4) ^ (row & 7);
        bf[j] = *(f16x8*)((char*)BS + row * 128 + ch * 16);
      }
#pragma unroll
      for (int i = 0; i < 4; i++)
#pragma unroll
        for (int j = 0; j < 4; j++)
          acc[i][j] = __builtin_amdgcn_mfma_f32_16x16x32_f16(af[i], bf[j], acc[i][j], 0, 0, 0);
    }
  }

  // ---- epilogues ----
  if (MODE == MODE_K) {
    float ksm[4] = {0.f, 0.f, 0.f, 0.f};
#pragma unroll
    for (int i = 0; i < 4; i++)
#pragma unroll
      for (int j = 0; j < 4; j++)
#pragma unroll
        for (int r = 0; r < 4; r++) {
          int row = wr * 64 + i * 16 + l4 * 4 + r;
          float x = phi_f(acc[i][j][r]);
          if (mask[m0 + row] == 0) x = 0.f;
          ksm[j] += x;
          C[(size_t)(c0 + row) * DIM + n0 + wc * 64 + j * 16 + l15] = (f16)x;
        }
#pragma unroll
    for (int j = 0; j < 4; j++) {
      float v = ksm[j];
      v += __shfl_xor(v, 16);
      v += __shfl_xor(v, 32);
      if (l4 == 0)
        pKs[(size_t)(mb * 2 + wr) * 1024 + n0 + wc * 64 + j * 16 + l15] = (f16)v;
    }
  } else if (MODE == MODE_V) {
#pragma unroll
    for (int i = 0; i < 4; i++)
#pragma unroll
      for (int j = 0; j < 4; j++)
#pragma unroll
        for (int r = 0; r < 4; r++) {
          int row = wr * 64 + i * 16 + l4 * 4 + r;
          C[(size_t)(c0 + row) * DIM + n0 + wc * 64 + j * 16 + l15] = (f16)acc[i][j][r];
        }
  } else {  // MODE_Q: phi + in-register Z + scale
#pragma unroll
    for (int i = 0; i < 4; i++)
#pragma unroll
      for (int r = 0; r < 4; r++) {
        float p0 = phi_f(acc[i][0][r]);
        float p1 = phi_f(acc[i][1][r]);
        float p2 = phi_f(acc[i][2][r]);
        float p3 = phi_f(acc[i][3][r]);
        float den = p0 * ksv[0] + p1 * ksv[1] + p2 * ksv[2] + p3 * ksv[3];
        den += __shfl_xor(den, 1);
        den += __shfl_xor(den, 2);
        den += __shfl_xor(den, 4);
        den += __shfl_xor(den, 8);
        float z = 1.f / den;
        int row = wr * 64 + i * 16 + l4 * 4 + r;
        size_t base = (size_t)(c0 + row) * DIM + n0 + wc * 64 + l15;
        C[base] = (f16)(p0 * z);
        C[base + 16] = (f16)(p1 * z);
        C[base + 32] = (f16)(p2 * z);
        C[base + 48] = (f16)(p3 * z);
      }
  }
}

// ============ OUT GEMM: out = Ap @ M_b^T + bo (f16-both, swizzled, fp32 out) ============
__global__ __launch_bounds__(256) void gemm_out(const f16* __restrict__ Ap,
                                                const f16* __restrict__ Mh,
                                                const float* __restrict__ bo,
                                                float* __restrict__ Out,
                                                int m_base) {
  __shared__ __attribute__((aligned(16))) f16 AS[128 * 64];  // 16 KB
  __shared__ __attribute__((aligned(16))) f16 BS[128 * 64];  // 16 KB
  const int tid = threadIdx.x;
  const int lane = tid & 63;
  const int l15 = lane & 15, l4 = lane >> 4;
  const int w = tid >> 6, wr = w >> 1, wc = w & 1;
  int nb, mb;
  swz_8x64(nb, mb);
  const int n0 = nb * 128;
  const int c0 = mb * 128;
  const int b = (m_base + c0) >> 12;
  const f16* B = Mh + (size_t)b * 1048576;

  f32x4 acc[4][4];
#pragma unroll
  for (int j = 0; j < 4; j++) {
    float bv = bo[n0 + wc * 64 + j * 16 + l15];
#pragma unroll
    for (int i = 0; i < 4; i++) acc[i][j] = (f32x4){bv, bv, bv, bv};
  }

  for (int kt = 0; kt < DIM; kt += 64) {
    __syncthreads();
#pragma unroll
    for (int c = 0; c < 4; c++) {
      int row = w * 32 + c * 8 + (lane >> 3);
      int sc = (lane & 7) ^ (row & 7);
      g2l16(Ap + (size_t)(c0 + row) * DIM + kt + sc * 8,
            (char*)AS + w * 4096 + c * 1024);
      g2l16(B + (size_t)(n0 + row) * DIM + kt + sc * 8,
            (char*)BS + w * 4096 + c * 1024);
    }
    __syncthreads();
#pragma unroll
    for (int ks = 0; ks < 2; ks++) {
      f16x8 af[4], bf[4];
#pragma unroll
      for (int i = 0; i < 4; i++) {
        int row = wr * 64 + i * 16 + l15;
        int ch = (ks * 4 + l4) ^ (row & 7);
        af[i] = *(f16x8*)((char*)AS + row * 128 + ch * 16);
      }
#pragma unroll
      for (int j = 0; j < 4; j++) {
        int row = wc * 64 + j * 16 + l15;
        int ch = (ks * 4 + l4) ^ (row & 7);
        bf[j] = *(f16x8*)((char*)BS + row * 128 + ch * 16);
      }
#pragma unroll
      for (int i = 0; i < 4; i++)
#pragma unroll
        for (int j = 0; j < 4; j++)
          acc[i][j] = __builtin_amdgcn_mfma_f32_16x16x32_f16(af[i], bf[j], acc[i][j], 0, 0, 0);
    }
  }

#pragma unroll
  for (int i = 0; i < 4; i++)
#pragma unroll
    for (int j = 0; j < 4; j++) {
      const int rl = wr * 64 + i * 16 + l4 * 4;
      const int gn = n0 + wc * 64 + j * 16 + l15;
#pragma unroll
      for (int r = 0; r < 4; r++)
        Out[(size_t)(m_base + c0 + rl + r) * DIM + gn] = acc[i][j][r];
    }
}

// ---------------- KV via MFMA (unchanged) ----------------
__global__ __launch_bounds__(256) void kv_mfma(const f16* __restrict__ Kp,
                                               const f16* __restrict__ Vp,
                                               f16* __restrict__ pKV) {
  __shared__ f16 KT[64][66];
  __shared__ f16 VT[64][66];
  const int tid = threadIdx.x;
  const int lane = tid & 63;
  const int l15 = lane & 15, l4 = lane >> 4, w = tid >> 6;
  const int h = blockIdx.x;
  const int ck = blockIdx.y;
  const int bl = ck >> 3;
  const int srow0 = bl * 4096 + (ck & 7) * 512;
  const int s_loc = tid >> 2;
  const int c0 = (tid & 3) * 16;

  f32x4 acc[4];
#pragma unroll
  for (int j = 0; j < 4; j++) acc[j] = (f32x4){0.f, 0.f, 0.f, 0.f};

  for (int sub = 0; sub < 8; sub++) {
    const size_t gbase = (size_t)(srow0 + sub * 64 + s_loc) * DIM + h * 64 + c0;
    f16x8 k0 = *(const f16x8*)(Kp + gbase);
    f16x8 k1 = *(const f16x8*)(Kp + gbase + 8);
    f16x8 v0 = *(const f16x8*)(Vp + gbase);
    f16x8 v1 = *(const f16x8*)(Vp + gbase + 8);
    __syncthreads();
#pragma unroll
    for (int q = 0; q < 8; q++) {
      KT[c0 + q][s_loc] = k0[q];
      KT[c0 + 8 + q][s_loc] = k1[q];
      VT[c0 + q][s_loc] = v0[q];
      VT[c0 + 8 + q][s_loc] = v1[q];
    }
    __syncthreads();
#pragma unroll
    for (int ks = 0; ks < 2; ks++) {
      f16x8 af = *(f16x8*)&KT[w * 16 + l15][ks * 32 + l4 * 8];
#pragma unroll
      for (int j = 0; j < 4; j++) {
        f16x8 bfr = *(f16x8*)&VT[j * 16 + l15][ks * 32 + l4 * 8];
        acc[j] = __builtin_amdgcn_mfma_f32_16x16x32_f16(af, bfr, acc[j], 0, 0, 0);
      }
    }
  }
  f16* dst = pKV + (size_t)(h * 16 + ck) * 4096;
#pragma unroll
  for (int j = 0; j < 4; j++)
#pragma unroll
    for (int r = 0; r < 4; r++)
      dst[(w * 16 + l4 * 4 + r) * 64 + j * 16 + l15] = (f16)acc[j][r];
}

// ---------------- reduce (unchanged) ----------------
__global__ __launch_bounds__(256) void kv_reduce(const f16* __restrict__ pKV,
                                                 const f16* __restrict__ pKs,
                                                 f16* __restrict__ KVdh,
                                                 float* __restrict__ Ksum,
                                                 int half) {
  const int bh_l = blockIdx.x;
  const int h = bh_l & 15, bl = bh_l >> 4;
  const int bh = half * 32 + bh_l;
  const int tid = threadIdx.x;
  for (int cell = tid; cell < 4096; cell += 256) {
    float s = 0.f;
#pragma unroll
    for (int c = 0; c < 8; c++) s += (float)pKV[(size_t)(h * 16 + bl * 8 + c) * 4096 + cell];
    KVdh[(size_t)bh * 4096 + cell] = (f16)s;
  }
  if (tid < 64) {
    float s = 0.f;
#pragma unroll
    for (int y = 0; y < 64; y++) s += (float)pKs[(size_t)(bl * 64 + y) * 1024 + h * 64 + tid];
    Ksum[bh * 64 + tid] = s + 1e-6f;
  }
}

// ---------------- M precompute (unchanged) ----------------
__global__ __launch_bounds__(256) void m_kernel(const f16* __restrict__ Woh,
                                                const f16* __restrict__ KVdh,
                                                f16* __restrict__ Mh) {
  __shared__ __attribute__((aligned(16))) f16 As[128][64];
  __shared__ __attribute__((aligned(16))) f16 Bs[64][64];
  const int tid = threadIdx.x;
  const int lane = tid & 63;
  const int l15 = lane & 15, l4 = lane >> 4, w = tid >> 6;
  const int n0 = blockIdx.x * 128;
  const int bh = blockIdx.y;
  const int b = bh >> 4, h = bh & 15;

#pragma unroll
  for (int c = 0; c < 4; c++) {
    int row = w * 32 + c * 8 + (lane >> 3);
    int col = (lane & 7) * 8;
    g2l16(Woh + (size_t)(n0 + row) * DIM + h * 64 + col, (char*)As + w * 4096 + c * 1024);
  }
#pragma unroll
  for (int c = 0; c < 2; c++) {
    int row = w * 16 + c * 8 + (lane >> 3);
    int col = (lane & 7) * 8;
    g2l16(KVdh + (size_t)bh * 4096 + row * 64 + col, (char*)Bs + w * 2048 + c * 1024);
  }
  __syncthreads();

  f32x4 acc[2][4];
#pragma unroll
  for (int i = 0; i < 2; i++)
#pragma unroll
    for (int j = 0; j < 4; j++) acc[i][j] = (f32x4){0.f, 0.f, 0.f, 0.f};
#pragma unroll
  for (int ks = 0; ks < 2; ks++) {
    f16x8 af[2], bfr[4];
#pragma unroll
    for (int i = 0; i < 2; i++)
      af[i] = *(f16x8*)&As[w * 32 + i * 16 + l15][ks * 32 + l4 * 8];
#pragma unroll
    for (int j = 0; j < 4; j++)
      bfr[j] = *(f16x8*)&Bs[j * 16 + l15][ks * 32 + l4 * 8];
#pragma unroll
    for (int i = 0; i < 2; i++)
#pragma unroll
      for (int j = 0; j < 4; j++)
        acc[i][j] = __builtin_amdgcn_mfma_f32_16x16x32_f16(af[i], bfr[j], acc[i][j], 0, 0, 0);
  }
#pragma unroll
  for (int i = 0; i < 2; i++)
#pragma unroll
    for (int j = 0; j < 4; j++)
#pragma unroll
      for (int r = 0; r < 4; r++) {
        int nl = n0 + w * 32 + i * 16 + l4 * 4 + r;
        Mh[(size_t)b * 1048576 + (size_t)nl * DIM + h * 64 + j * 16 + l15] = (f16)acc[i][j][r];
      }
}

extern "C" void kernel_launch(void* const* d_in, const int* in_sizes, int n_in,
                              void* d_out, int out_size, void* d_ws, size_t ws_size,
                              hipStream_t stream) {
  (void)in_sizes; (void)n_in; (void)out_size; (void)ws_size;
  const float* query = (const float*)d_in[0];
  const float* key = (const float*)d_in[1];
  const float* value = (const float*)d_in[2];
  const int* kmask = (const int*)d_in[3];
  const float* Wq = (const float*)d_in[4];
  const float* bq = (const float*)d_in[5];
  const float* Wk = (const float*)d_in[6];
  const float* bk = (const float*)d_in[7];
  const float* Wv = (const float*)d_in[8];
  const float* bv = (const float*)d_in[9];
  const float* Wo = (const float*)d_in[10];
  const float* bo = (const float*)d_in[11];

  // workspace (peak ~58.8 MiB; ws_size >= 60 MiB proven in R6)
  char* ws = (char*)d_ws;
  const size_t MB = 1 << 20;
  f16* W0 = (f16*)(ws);                // Wkh
  f16* W1 = (f16*)(ws + 2 * MB);       // Wvh
  f16* W2 = (f16*)(ws + 4 * MB);       // Wqh
  f16* W3 = (f16*)(ws + 6 * MB);       // Woh
  f16* Xf = (f16*)(ws + 8 * MB);       // 16 MiB f16 input half (key/value/query, reused)
  f16* Kp = (f16*)(ws + 24 * MB);      // 16 MiB (half) ; stage2: Ap
  f16* Vp = (f16*)(ws + 40 * MB);      // 16 MiB (half) ; stage2: Mh (8 MiB)
  f16* pKV = (f16*)(ws + 56 * MB);     // 2 MiB
  f16* pKs = (f16*)(ws + 58 * MB);     // 256 KiB ([128][1024] per half)
  f16* KVdh = (f16*)(ws + 58 * MB + 256 * 1024);      // 512 KiB
  float* Ksum = (float*)(ws + 58 * MB + 768 * 1024);  // 16 KiB
  f16* Ap = Kp;
  f16* Mh = Vp;

  dim3 blk(256);
  dim3 ghalf(8, 64);
  cvt8<<<512, blk, 0, stream>>>(Wk, W0);
  cvt8<<<512, blk, 0, stream>>>(Wv, W1);
  cvt8<<<512, blk, 0, stream>>>(Wq, W2);
  cvt8<<<512, blk, 0, stream>>>(Wo, W3);

  // stage 1: per-half cvt + K/V projections (f16-both) + MFMA KV partials
  for (int half = 0; half < 2; half++) {
    int mb = half * 8192;
    cvt8<<<4096, blk, 0, stream>>>(key + (size_t)mb * DIM, Xf);
    gemm_f16<MODE_K><<<ghalf, blk, 0, stream>>>(Xf, W0, bk, kmask, Kp, pKs, nullptr, mb);
    cvt8<<<4096, blk, 0, stream>>>(value + (size_t)mb * DIM, Xf);
    gemm_f16<MODE_V><<<ghalf, blk, 0, stream>>>(Xf, W1, bv, nullptr, Vp, nullptr, nullptr, mb);
    kv_mfma<<<dim3(16, 16), blk, 0, stream>>>(Kp, Vp, pKV);
    kv_reduce<<<32, blk, 0, stream>>>(pKV, pKs, KVdh, Ksum, half);
  }

  // stage 2: M precompute, per-half cvt + Q -> A' and OUT
  m_kernel<<<dim3(8, 64), blk, 0, stream>>>(W3, KVdh, Mh);
  for (int half = 0; half < 2; half++) {
    int mb = half * 8192;
    cvt8<<<4096, blk, 0, stream>>>(query + (size_t)mb * DIM, Xf);
    gemm_f16<MODE_Q><<<ghalf, blk, 0, stream>>>(Xf, W2, bq, nullptr, Ap, nullptr, Ksum, mb);
    gemm_out<<<ghalf, blk, 0, stream>>>(Ap, Mh, bo, (float*)d_out, mb);
  }
}